// Round 1
// baseline (292.150 us; speedup 1.0000x reference)
//
#include <hip/hip_runtime.h>
#include <hip/hip_bf16.h>

#define CH 512

typedef __attribute__((ext_vector_type(8))) short short8;
typedef __attribute__((ext_vector_type(4))) float f32x4;

static __device__ __forceinline__ ushort f2b(float f) {
  union { __hip_bfloat16 b; ushort u; } c;
  c.b = __float2bfloat16(f);
  return c.u;
}

__global__ void k_zero(int* p, int n) {
  int i = blockIdx.x * blockDim.x + threadIdx.x;
  if (i < n) p[i] = 0;
}

// Detect whether edge_index was passed as int64 (odd int32 words == 0) or int32.
__global__ void k_detect(const int* ei, int* flag) {
  if (threadIdx.x == 0 && blockIdx.x == 0) {
    int zeros = 0;
    for (int j = 1; j < 32; j += 2) zeros += (ei[j] == 0) ? 1 : 0;
    *flag = (zeros >= 14) ? 1 : 0;
  }
}

__global__ void k_cvt_edges(const int* ei, const int* flag, int* s32, int* d32, int E) {
  int e = blockIdx.x * blockDim.x + threadIdx.x;
  if (e >= E) return;
  if (*flag) {
    const long long* p = (const long long*)ei;
    s32[e] = (int)p[e];
    d32[e] = (int)p[e + E];
  } else {
    s32[e] = ei[e];
    d32[e] = ei[e + E];
  }
}

__global__ void k_count(const int* s32, const int* d32, int* outdeg, int* indeg, int E) {
  int e = blockIdx.x * blockDim.x + threadIdx.x;
  if (e >= E) return;
  atomicAdd(&outdeg[s32[e]], 1);
  atomicAdd(&indeg[d32[e]], 1);
}

__global__ void k_dinv(const int* indeg, float* dinv, int N) {
  int i = blockIdx.x * blockDim.x + threadIdx.x;
  if (i < N) dinv[i] = rsqrtf((float)(indeg[i] + 1));  // +1 self loop; always > 0
}

__global__ __launch_bounds__(1024) void k_scan(const int* outdeg, int* rs, int* cursor, int N) {
  __shared__ int part[1024];
  int t = threadIdx.x;
  int per = (N + 1023) >> 10;
  int base = t * per;
  int s = 0;
  for (int j = 0; j < per; ++j) {
    int i = base + j;
    if (i < N) s += outdeg[i] + 1;  // +1 self loop
  }
  part[t] = s;
  __syncthreads();
  for (int off = 1; off < 1024; off <<= 1) {
    int v = part[t];
    int u = (t >= off) ? part[t - off] : 0;
    __syncthreads();
    part[t] = v + u;
    __syncthreads();
  }
  int run = (t == 0) ? 0 : part[t - 1];
  for (int j = 0; j < per; ++j) {
    int i = base + j;
    if (i < N) {
      rs[i] = run;
      cursor[i] = run;
      run += outdeg[i] + 1;
    }
  }
  if (t == 0) rs[N] = part[1023];
}

__global__ void k_fill(const int* s32, const int* d32, const float* dinv,
                       int* cursor, int* col, float* wgt, int E, int N) {
  int e = blockIdx.x * blockDim.x + threadIdx.x;
  if (e < E) {
    int s = s32[e], d = d32[e];
    int pos = atomicAdd(&cursor[s], 1);
    col[pos] = d;
    wgt[pos] = dinv[s] * dinv[d];
  } else if (e < E + N) {
    int i = e - E;
    int pos = atomicAdd(&cursor[i], 1);
    col[pos] = i;
    float di = dinv[i];
    wgt[pos] = di * di;
  }
}

__global__ void k_cast_x(const float* x, ushort* xb, int n4) {
  int i = blockIdx.x * blockDim.x + threadIdx.x;
  if (i >= n4) return;
  float4 v = ((const float4*)x)[i];
  ushort4 o = { f2b(v.x), f2b(v.y), f2b(v.z), f2b(v.w) };
  ((ushort4*)xb)[i] = o;
}

// W[k][n] (512x512) -> WT[n][k] bf16
__global__ void k_cast_wt(const float* W, ushort* WT) {
  int idx = blockIdx.x * blockDim.x + threadIdx.x;
  if (idx >= CH * CH) return;
  int n = idx >> 9, k = idx & 511;
  WT[idx] = f2b(W[(k << 9) + n]);
}

// C[M,512] = A[M,512](bf16) @ B (given as BT[n][k] bf16) + bias, f32 out.
// Block: 256 thr = 4 waves; wave computes 16 rows x 64 cols; block 64x64.
__global__ __launch_bounds__(256) void k_gemm(const ushort* __restrict__ A,
                                              const ushort* __restrict__ BT,
                                              const float* __restrict__ bias,
                                              float* __restrict__ Cout, int M) {
  int wave = threadIdx.x >> 6;
  int lane = threadIdx.x & 63;
  int l15 = lane & 15;
  int lh = lane >> 4;
  int row0 = blockIdx.x * 64 + wave * 16;
  int col0 = blockIdx.y * 64;
  int arow = row0 + l15;
  int arc = (arow < M) ? arow : 0;
  const ushort* aptr = A + (size_t)arc * CH + lh * 8;
  const ushort* bptr = BT + (size_t)(col0 + l15) * CH + lh * 8;
  f32x4 acc0 = {}, acc1 = {}, acc2 = {}, acc3 = {};
  for (int k0 = 0; k0 < CH; k0 += 32) {
    short8 a = *(const short8*)(aptr + k0);
    short8 b0 = *(const short8*)(bptr + k0);
    short8 b1 = *(const short8*)(bptr + 16 * CH + k0);
    short8 b2 = *(const short8*)(bptr + 32 * CH + k0);
    short8 b3 = *(const short8*)(bptr + 48 * CH + k0);
    acc0 = __builtin_amdgcn_mfma_f32_16x16x32_bf16(a, b0, acc0, 0, 0, 0);
    acc1 = __builtin_amdgcn_mfma_f32_16x16x32_bf16(a, b1, acc1, 0, 0, 0);
    acc2 = __builtin_amdgcn_mfma_f32_16x16x32_bf16(a, b2, acc2, 0, 0, 0);
    acc3 = __builtin_amdgcn_mfma_f32_16x16x32_bf16(a, b3, acc3, 0, 0, 0);
  }
  f32x4 accs[4] = { acc0, acc1, acc2, acc3 };
  // C/D layout (verified m89/m91): col = lane&15, row = (lane>>4)*4 + reg
  #pragma unroll
  for (int j = 0; j < 4; ++j) {
    int c = col0 + j * 16 + l15;
    float bi = bias[c];
    #pragma unroll
    for (int r = 0; r < 4; ++r) {
      int row = row0 + lh * 4 + r;
      if (row < M) Cout[(size_t)row * CH + c] = accs[j][r] + bi;
    }
  }
}

// out[i,:] = sum_j wgt[j] * h[col[j],:], one block per node, 2 channels/thread
__global__ __launch_bounds__(256) void k_agg(const float* __restrict__ h,
                                             const int* __restrict__ rs,
                                             const int* __restrict__ col,
                                             const float* __restrict__ wgt,
                                             float* __restrict__ out) {
  int i = blockIdx.x;
  int t = threadIdx.x;
  int beg = rs[i], end = rs[i + 1];
  float a0 = 0.f, a1 = 0.f;
  for (int j = beg; j < end; ++j) {
    float w = wgt[j];
    const float* hp = h + (size_t)col[j] * CH;
    a0 += w * hp[t];
    a1 += w * hp[t + 256];
  }
  out[(size_t)i * CH + t] = a0;
  out[(size_t)i * CH + t + 256] = a1;
}

__global__ __launch_bounds__(256) void k_bn_stats(const float* __restrict__ a,
                                                  float* __restrict__ stats, int N) {
  int t = threadIdx.x;
  float s0 = 0.f, q0 = 0.f, s1 = 0.f, q1 = 0.f;
  for (int i = blockIdx.x; i < N; i += gridDim.x) {
    float v0 = a[(size_t)i * CH + t];
    float v1 = a[(size_t)i * CH + t + 256];
    s0 += v0; q0 += v0 * v0;
    s1 += v1; q1 += v1 * v1;
  }
  atomicAdd(&stats[t], s0);
  atomicAdd(&stats[t + 256], s1);
  atomicAdd(&stats[CH + t], q0);
  atomicAdd(&stats[CH + t + 256], q1);
}

__global__ void k_bn_scale(const float* stats, const float* gamma, const float* beta,
                           float* scale, float* shift, float invN) {
  int c = blockIdx.x * blockDim.x + threadIdx.x;
  if (c >= CH) return;
  float mu = stats[c] * invN;
  float var = stats[CH + c] * invN - mu * mu;  // biased var, matches jnp.var
  float s = gamma[c] * rsqrtf(var + 1e-5f);
  scale[c] = s;
  shift[c] = beta[c] - s * mu;
}

__global__ void k_bn_apply(const float* __restrict__ a, const float* __restrict__ scale,
                           const float* __restrict__ shift, ushort* __restrict__ hb, int n4) {
  int i = blockIdx.x * blockDim.x + threadIdx.x;
  if (i >= n4) return;
  float4 v = ((const float4*)a)[i];
  float4 sc = ((const float4*)scale)[i & 127];
  float4 sh = ((const float4*)shift)[i & 127];
  float r0 = fmaxf(v.x * sc.x + sh.x, 0.f);
  float r1 = fmaxf(v.y * sc.y + sh.y, 0.f);
  float r2 = fmaxf(v.z * sc.z + sh.z, 0.f);
  float r3 = fmaxf(v.w * sc.w + sh.w, 0.f);
  ushort4 o = { f2b(r0), f2b(r1), f2b(r2), f2b(r3) };
  ((ushort4*)hb)[i] = o;
}

extern "C" void kernel_launch(void* const* d_in, const int* in_sizes, int n_in,
                              void* d_out, int out_size, void* d_ws, size_t ws_size,
                              hipStream_t stream) {
  const float* x     = (const float*)d_in[0];
  const float* W1    = (const float*)d_in[1];
  const float* b1    = (const float*)d_in[2];
  const float* gamma = (const float*)d_in[3];
  const float* beta  = (const float*)d_in[4];
  const float* W2    = (const float*)d_in[5];
  const float* b2    = (const float*)d_in[6];
  const int*   ei    = (const int*)d_in[7];
  const int N = in_sizes[0] / CH;
  const int E = in_sizes[7] / 2;
  float* out = (float*)d_out;

  char* wsp = (char*)d_ws;
  size_t off = 0;
  auto alloc = [&](size_t b) { char* p = wsp + off; off += (b + 255) & ~(size_t)255; return p; };
  int*    outdeg = (int*)alloc((size_t)N * 4);         // zeroed below
  int*    indeg  = (int*)alloc((size_t)N * 4);         // zeroed below
  float*  stats  = (float*)alloc(1024 * 4);            // zeroed below
  float*  scale  = (float*)alloc(CH * 4);
  float*  shift  = (float*)alloc(CH * 4);
  int*    flag   = (int*)alloc(4);
  int*    s32    = (int*)alloc((size_t)E * 4);
  int*    d32    = (int*)alloc((size_t)E * 4);
  float*  dinv   = (float*)alloc((size_t)N * 4);
  int*    rs     = (int*)alloc((size_t)(N + 1) * 4);
  int*    cursor = (int*)alloc((size_t)N * 4);
  int*    colx   = (int*)alloc((size_t)(E + N) * 4);
  float*  wgt    = (float*)alloc((size_t)(E + N) * 4);
  ushort* xb     = (ushort*)alloc((size_t)N * CH * 2);
  ushort* w1t    = (ushort*)alloc((size_t)CH * CH * 2);
  ushort* w2t    = (ushort*)alloc((size_t)CH * CH * 2);
  ushort* h3b    = (ushort*)alloc((size_t)N * CH * 2);
  float*  h1     = (float*)alloc((size_t)N * CH * 4);  // also reused as GEMM2 out
  float*  a1     = (float*)alloc((size_t)N * CH * 4);

  // zero the contiguous [outdeg .. stats] span
  int zn = (int)(((char*)stats - (char*)outdeg) / 4) + 1024;
  k_zero<<<dim3((zn + 255) / 256), dim3(256), 0, stream>>>(outdeg, zn);
  k_detect<<<1, 1, 0, stream>>>(ei, flag);
  int eb = (E + 255) / 256;
  k_cvt_edges<<<eb, 256, 0, stream>>>(ei, flag, s32, d32, E);
  k_count<<<eb, 256, 0, stream>>>(s32, d32, outdeg, indeg, E);
  k_dinv<<<(N + 255) / 256, 256, 0, stream>>>(indeg, dinv, N);
  k_scan<<<1, 1024, 0, stream>>>(outdeg, rs, cursor, N);
  k_fill<<<(E + N + 255) / 256, 256, 0, stream>>>(s32, d32, dinv, cursor, colx, wgt, E, N);
  int n4 = N * CH / 4;
  k_cast_x<<<(n4 + 255) / 256, 256, 0, stream>>>(x, xb, n4);
  k_cast_wt<<<(CH * CH + 255) / 256, 256, 0, stream>>>(W1, w1t);
  k_cast_wt<<<(CH * CH + 255) / 256, 256, 0, stream>>>(W2, w2t);
  dim3 gg((N + 63) / 64, CH / 64);
  k_gemm<<<gg, 256, 0, stream>>>(xb, w1t, b1, h1, N);
  k_agg<<<N, 256, 0, stream>>>(h1, rs, colx, wgt, a1);
  k_bn_stats<<<256, 256, 0, stream>>>(a1, stats, N);
  k_bn_scale<<<2, 256, 0, stream>>>(stats, gamma, beta, scale, shift, 1.0f / (float)N);
  k_bn_apply<<<(n4 + 255) / 256, 256, 0, stream>>>(a1, scale, shift, h3b, n4);
  k_gemm<<<gg, 256, 0, stream>>>(h3b, w2t, b2, h1, N);
  k_agg<<<N, 256, 0, stream>>>(h1, rs, colx, wgt, out);
}

// Round 2
// 228.371 us; speedup vs baseline: 1.2793x; 1.2793x over previous
//
#include <hip/hip_runtime.h>
#include <hip/hip_bf16.h>

#define CH 512
#define BM 128
#define BN 128
#define BK 64

typedef __attribute__((ext_vector_type(8))) short short8;
typedef __attribute__((ext_vector_type(4))) float f32x4;

static __device__ __forceinline__ ushort f2b(float f) {
  union { __hip_bfloat16 b; ushort u; } c;
  c.b = __float2bfloat16(f);
  return c.u;
}

__global__ void k_zero(int* p, int n) {
  int i = blockIdx.x * blockDim.x + threadIdx.x;
  if (i < n) p[i] = 0;
}

// Detect whether edge_index was passed as int64 (odd int32 words == 0) or int32.
__global__ void k_detect(const int* ei, int* flag) {
  if (threadIdx.x == 0 && blockIdx.x == 0) {
    int zeros = 0;
    for (int j = 1; j < 32; j += 2) zeros += (ei[j] == 0) ? 1 : 0;
    *flag = (zeros >= 14) ? 1 : 0;
  }
}

__global__ void k_cvt_edges(const int* ei, const int* flag, int* s32, int* d32, int E) {
  int e = blockIdx.x * blockDim.x + threadIdx.x;
  if (e >= E) return;
  if (*flag) {
    const long long* p = (const long long*)ei;
    s32[e] = (int)p[e];
    d32[e] = (int)p[e + E];
  } else {
    s32[e] = ei[e];
    d32[e] = ei[e + E];
  }
}

__global__ void k_count(const int* s32, const int* d32, int* outdeg, int* indeg, int E) {
  int e = blockIdx.x * blockDim.x + threadIdx.x;
  if (e >= E) return;
  atomicAdd(&outdeg[s32[e]], 1);
  atomicAdd(&indeg[d32[e]], 1);
}

__global__ void k_dinv(const int* indeg, float* dinv, int N) {
  int i = blockIdx.x * blockDim.x + threadIdx.x;
  if (i < N) dinv[i] = rsqrtf((float)(indeg[i] + 1));  // +1 self loop; always > 0
}

__global__ __launch_bounds__(1024) void k_scan(const int* outdeg, int* rs, int* cursor, int N) {
  __shared__ int part[1024];
  int t = threadIdx.x;
  int per = (N + 1023) >> 10;
  int base = t * per;
  int s = 0;
  for (int j = 0; j < per; ++j) {
    int i = base + j;
    if (i < N) s += outdeg[i] + 1;  // +1 self loop
  }
  part[t] = s;
  __syncthreads();
  for (int off = 1; off < 1024; off <<= 1) {
    int v = part[t];
    int u = (t >= off) ? part[t - off] : 0;
    __syncthreads();
    part[t] = v + u;
    __syncthreads();
  }
  int run = (t == 0) ? 0 : part[t - 1];
  for (int j = 0; j < per; ++j) {
    int i = base + j;
    if (i < N) {
      rs[i] = run;
      cursor[i] = run;
      run += outdeg[i] + 1;
    }
  }
  if (t == 0) rs[N] = part[1023];
}

__global__ void k_fill(const int* s32, const int* d32, const float* dinv,
                       int* cursor, int* col, float* wgt, int E, int N) {
  int e = blockIdx.x * blockDim.x + threadIdx.x;
  if (e < E) {
    int s = s32[e], d = d32[e];
    int pos = atomicAdd(&cursor[s], 1);
    col[pos] = d;
    wgt[pos] = dinv[s] * dinv[d];
  } else if (e < E + N) {
    int i = e - E;
    int pos = atomicAdd(&cursor[i], 1);
    col[pos] = i;
    float di = dinv[i];
    wgt[pos] = di * di;
  }
}

// cast x (N*CH floats) -> bf16, zero-pad rows up to M_pad
__global__ void k_cast_x(const float* x, ushort* xb, int n4, int n4p) {
  int i = blockIdx.x * blockDim.x + threadIdx.x;
  if (i >= n4p) return;
  ushort4 o;
  if (i < n4) {
    float4 v = ((const float4*)x)[i];
    o = (ushort4){ f2b(v.x), f2b(v.y), f2b(v.z), f2b(v.w) };
  } else {
    o = (ushort4){ 0, 0, 0, 0 };
  }
  ((ushort4*)xb)[i] = o;
}

// W[k][n] (512x512) -> WT[n][k] bf16, both weights in one launch
__global__ void k_cast_wt2(const float* W1, ushort* WT1, const float* W2, ushort* WT2) {
  int idx = blockIdx.x * blockDim.x + threadIdx.x;
  if (idx >= 2 * CH * CH) return;
  const float* W = (idx < CH * CH) ? W1 : W2;
  ushort* WT = (idx < CH * CH) ? WT1 : WT2;
  int j = idx & (CH * CH - 1);
  int n = j >> 9, k = j & 511;
  WT[j] = f2b(W[(k << 9) + n]);
}

// C[M_pad,512] = A[M_pad,512](bf16) @ B(BT[n][k] bf16) + bias, f32 out.
// m97 structure: 128x128 tile, BK=64, global_load_lds(16B), 4 waves, 64x64/wave.
__global__ __launch_bounds__(256) void k_gemm(const ushort* __restrict__ A,
                                              const ushort* __restrict__ BT,
                                              const float* __restrict__ bias,
                                              float* __restrict__ Cout) {
  __shared__ __align__(16) ushort As[BM * BK];
  __shared__ __align__(16) ushort Bs[BN * BK];
  const int t = threadIdx.x;
  const int wave = t >> 6;
  const int lane = t & 63;
  const int l15 = lane & 15;
  const int lh = lane >> 4;
  const int wm = wave >> 1;   // 0..1
  const int wn = wave & 1;    // 0..1
  const int row0 = blockIdx.x * BM;
  const int col0 = blockIdx.y * BN;

  // staging geometry: issue i covers LDS bytes [i*4096, (i+1)*4096); thread t owns 16B
  const int o0 = t * 16;           // byte offset within a 4KB issue... combined below
  f32x4 acc[4][4] = {};

  #pragma unroll 1
  for (int kt = 0; kt < CH / BK; ++kt) {
    const int k0 = kt * BK;
    #pragma unroll
    for (int i = 0; i < 4; ++i) {
      int o = i * 4096 + o0;           // linear byte offset into As/Bs
      int row = o >> 7;                // /128B per row (64 bf16)
      int cb = o & 127;
      const ushort* sa = A + (size_t)(row0 + row) * CH + k0 + (cb >> 1);
      const ushort* sb = BT + (size_t)(col0 + row) * CH + k0 + (cb >> 1);
      __builtin_amdgcn_global_load_lds(
          (const __attribute__((address_space(1))) void*)sa,
          (__attribute__((address_space(3))) void*)((char*)As + o), 16, 0, 0);
      __builtin_amdgcn_global_load_lds(
          (const __attribute__((address_space(1))) void*)sb,
          (__attribute__((address_space(3))) void*)((char*)Bs + o), 16, 0, 0);
    }
    __syncthreads();
    #pragma unroll
    for (int ks = 0; ks < 2; ++ks) {
      short8 af[4], bf[4];
      #pragma unroll
      for (int mi = 0; mi < 4; ++mi)
        af[mi] = *(const short8*)&As[(wm * 64 + mi * 16 + l15) * BK + ks * 32 + lh * 8];
      #pragma unroll
      for (int ni = 0; ni < 4; ++ni)
        bf[ni] = *(const short8*)&Bs[(wn * 64 + ni * 16 + l15) * BK + ks * 32 + lh * 8];
      #pragma unroll
      for (int mi = 0; mi < 4; ++mi)
        #pragma unroll
        for (int ni = 0; ni < 4; ++ni)
          acc[mi][ni] = __builtin_amdgcn_mfma_f32_16x16x32_bf16(af[mi], bf[ni], acc[mi][ni], 0, 0, 0);
    }
    __syncthreads();
  }

  // C/D layout: col = lane&15, row = (lane>>4)*4 + reg  (verified m89/m91)
  #pragma unroll
  for (int ni = 0; ni < 4; ++ni) {
    int c = col0 + wn * 64 + ni * 16 + l15;
    float bi = bias[c];
    #pragma unroll
    for (int mi = 0; mi < 4; ++mi) {
      int row = row0 + wm * 64 + mi * 16 + lh * 4;
      #pragma unroll
      for (int r = 0; r < 4; ++r)
        Cout[(size_t)(row + r) * CH + c] = acc[mi][ni][r] + bi;
    }
  }
}

// out[i,:] = sum_j wgt[j] * h[col[j],:], one block per node, 2 channels/thread
__global__ __launch_bounds__(256) void k_agg(const float* __restrict__ h,
                                             const int* __restrict__ rs,
                                             const int* __restrict__ col,
                                             const float* __restrict__ wgt,
                                             float* __restrict__ out) {
  int i = blockIdx.x;
  int t = threadIdx.x;
  int beg = rs[i], end = rs[i + 1];
  float a0 = 0.f, a1 = 0.f;
  for (int j = beg; j < end; ++j) {
    float w = wgt[j];
    const float* hp = h + (size_t)col[j] * CH;
    a0 += w * hp[t];
    a1 += w * hp[t + 256];
  }
  out[(size_t)i * CH + t] = a0;
  out[(size_t)i * CH + t + 256] = a1;
}

__global__ __launch_bounds__(256) void k_bn_stats(const float* __restrict__ a,
                                                  float* __restrict__ stats, int N) {
  int t = threadIdx.x;
  float s0 = 0.f, q0 = 0.f, s1 = 0.f, q1 = 0.f;
  for (int i = blockIdx.x; i < N; i += gridDim.x) {
    float v0 = a[(size_t)i * CH + t];
    float v1 = a[(size_t)i * CH + t + 256];
    s0 += v0; q0 += v0 * v0;
    s1 += v1; q1 += v1 * v1;
  }
  atomicAdd(&stats[t], s0);
  atomicAdd(&stats[t + 256], s1);
  atomicAdd(&stats[CH + t], q0);
  atomicAdd(&stats[CH + t + 256], q1);
}

__global__ void k_bn_scale(const float* stats, const float* gamma, const float* beta,
                           float* scale, float* shift, float invN) {
  int c = blockIdx.x * blockDim.x + threadIdx.x;
  if (c >= CH) return;
  float mu = stats[c] * invN;
  float var = stats[CH + c] * invN - mu * mu;  // biased var, matches jnp.var
  float s = gamma[c] * rsqrtf(var + 1e-5f);
  scale[c] = s;
  shift[c] = beta[c] - s * mu;
}

// BN+ReLU+cast to bf16, zero-pad rows up to M_pad
__global__ void k_bn_apply(const float* __restrict__ a, const float* __restrict__ scale,
                           const float* __restrict__ shift, ushort* __restrict__ hb,
                           int n4, int n4p) {
  int i = blockIdx.x * blockDim.x + threadIdx.x;
  if (i >= n4p) return;
  ushort4 o;
  if (i < n4) {
    float4 v = ((const float4*)a)[i];
    float4 sc = ((const float4*)scale)[i & 127];
    float4 sh = ((const float4*)shift)[i & 127];
    float r0 = fmaxf(v.x * sc.x + sh.x, 0.f);
    float r1 = fmaxf(v.y * sc.y + sh.y, 0.f);
    float r2 = fmaxf(v.z * sc.z + sh.z, 0.f);
    float r3 = fmaxf(v.w * sc.w + sh.w, 0.f);
    o = (ushort4){ f2b(r0), f2b(r1), f2b(r2), f2b(r3) };
  } else {
    o = (ushort4){ 0, 0, 0, 0 };
  }
  ((ushort4*)hb)[i] = o;
}

extern "C" void kernel_launch(void* const* d_in, const int* in_sizes, int n_in,
                              void* d_out, int out_size, void* d_ws, size_t ws_size,
                              hipStream_t stream) {
  const float* x     = (const float*)d_in[0];
  const float* W1    = (const float*)d_in[1];
  const float* b1    = (const float*)d_in[2];
  const float* gamma = (const float*)d_in[3];
  const float* beta  = (const float*)d_in[4];
  const float* W2    = (const float*)d_in[5];
  const float* b2    = (const float*)d_in[6];
  const int*   ei    = (const int*)d_in[7];
  const int N = in_sizes[0] / CH;
  const int E = in_sizes[7] / 2;
  const int Mp = ((N + BM - 1) / BM) * BM;   // padded row count
  float* out = (float*)d_out;

  char* wsp = (char*)d_ws;
  size_t off = 0;
  auto alloc = [&](size_t b) { char* p = wsp + off; off += (b + 255) & ~(size_t)255; return p; };
  int*    outdeg = (int*)alloc((size_t)N * 4);         // zeroed below
  int*    indeg  = (int*)alloc((size_t)N * 4);         // zeroed below
  float*  stats  = (float*)alloc(1024 * 4);            // zeroed below
  float*  scale  = (float*)alloc(CH * 4);
  float*  shift  = (float*)alloc(CH * 4);
  int*    flag   = (int*)alloc(4);
  int*    s32    = (int*)alloc((size_t)E * 4);
  int*    d32    = (int*)alloc((size_t)E * 4);
  float*  dinv   = (float*)alloc((size_t)N * 4);
  int*    rs     = (int*)alloc((size_t)(N + 1) * 4);
  int*    cursor = (int*)alloc((size_t)N * 4);
  int*    colx   = (int*)alloc((size_t)(E + N) * 4);
  float*  wgt    = (float*)alloc((size_t)(E + N) * 4);
  ushort* xb     = (ushort*)alloc((size_t)Mp * CH * 2);
  ushort* w1t    = (ushort*)alloc((size_t)CH * CH * 2);
  ushort* w2t    = (ushort*)alloc((size_t)CH * CH * 2);
  ushort* h3b    = (ushort*)alloc((size_t)Mp * CH * 2);
  float*  h1     = (float*)alloc((size_t)Mp * CH * 4);  // GEMM1 & GEMM2 out (padded)
  float*  a1     = (float*)alloc((size_t)N * CH * 4);

  // zero the contiguous [outdeg .. stats] span
  int zn = (int)(((char*)stats - (char*)outdeg) / 4) + 1024;
  k_zero<<<dim3((zn + 255) / 256), dim3(256), 0, stream>>>(outdeg, zn);
  k_detect<<<1, 1, 0, stream>>>(ei, flag);
  int eb = (E + 255) / 256;
  k_cvt_edges<<<eb, 256, 0, stream>>>(ei, flag, s32, d32, E);
  k_count<<<eb, 256, 0, stream>>>(s32, d32, outdeg, indeg, E);
  k_dinv<<<(N + 255) / 256, 256, 0, stream>>>(indeg, dinv, N);
  k_scan<<<1, 1024, 0, stream>>>(outdeg, rs, cursor, N);
  k_fill<<<(E + N + 255) / 256, 256, 0, stream>>>(s32, d32, dinv, cursor, colx, wgt, E, N);
  int n4 = N * CH / 4, n4p = Mp * CH / 4;
  k_cast_x<<<(n4p + 255) / 256, 256, 0, stream>>>(x, xb, n4, n4p);
  k_cast_wt2<<<(2 * CH * CH + 255) / 256, 256, 0, stream>>>(W1, w1t, W2, w2t);
  dim3 gg(Mp / BM, CH / BN);
  k_gemm<<<gg, 256, 0, stream>>>(xb, w1t, b1, h1);
  k_agg<<<N, 256, 0, stream>>>(h1, rs, colx, wgt, a1);
  k_bn_stats<<<256, 256, 0, stream>>>(a1, stats, N);
  k_bn_scale<<<2, 256, 0, stream>>>(stats, gamma, beta, scale, shift, 1.0f / (float)N);
  k_bn_apply<<<(n4p + 255) / 256, 256, 0, stream>>>(a1, scale, shift, h3b, n4, n4p);
  k_gemm<<<gg, 256, 0, stream>>>(h3b, w2t, b2, h1);
  k_agg<<<N, 256, 0, stream>>>(h1, rs, colx, wgt, out);
}

// Round 3
// 211.551 us; speedup vs baseline: 1.3810x; 1.0795x over previous
//
#include <hip/hip_runtime.h>
#include <hip/hip_bf16.h>

#define CH 512
#define BM 128
#define BN 128
#define BK 64

typedef __attribute__((ext_vector_type(8))) short short8;
typedef __attribute__((ext_vector_type(4))) float f32x4;

static __device__ __forceinline__ ushort f2b(float f) {
  union { __hip_bfloat16 b; ushort u; } c;
  c.b = __float2bfloat16(f);
  return c.u;
}
static __device__ __forceinline__ float blo(uint u) { return __uint_as_float(u << 16); }
static __device__ __forceinline__ float bhi(uint u) { return __uint_as_float(u & 0xffff0000u); }

__global__ void k_zero(int* p, int n) {
  int i = blockIdx.x * blockDim.x + threadIdx.x;
  if (i < n) p[i] = 0;
}

// Detect whether edge_index was passed as int64 (odd int32 words == 0) or int32.
__global__ void k_detect(const int* ei, int* flag) {
  if (threadIdx.x == 0 && blockIdx.x == 0) {
    int zeros = 0;
    for (int j = 1; j < 32; j += 2) zeros += (ei[j] == 0) ? 1 : 0;
    *flag = (zeros >= 14) ? 1 : 0;
  }
}

__global__ void k_cvt_count(const int* ei, const int* flag, int* s32, int* d32,
                            int* outdeg, int* indeg, int E) {
  int e = blockIdx.x * blockDim.x + threadIdx.x;
  if (e >= E) return;
  int s, d;
  if (*flag) {
    const long long* p = (const long long*)ei;
    s = (int)p[e];
    d = (int)p[e + E];
  } else {
    s = ei[e];
    d = ei[e + E];
  }
  s32[e] = s;
  d32[e] = d;
  atomicAdd(&outdeg[s], 1);
  atomicAdd(&indeg[d], 1);
}

__global__ void k_dinv(const int* indeg, float* dinv, int N) {
  int i = blockIdx.x * blockDim.x + threadIdx.x;
  if (i < N) dinv[i] = rsqrtf((float)(indeg[i] + 1));  // +1 self loop; always > 0
}

__global__ __launch_bounds__(1024) void k_scan(const int* outdeg, int* rs, int* cursor, int N) {
  __shared__ int part[1024];
  int t = threadIdx.x;
  int per = (N + 1023) >> 10;
  int base = t * per;
  int s = 0;
  for (int j = 0; j < per; ++j) {
    int i = base + j;
    if (i < N) s += outdeg[i] + 1;  // +1 self loop
  }
  part[t] = s;
  __syncthreads();
  for (int off = 1; off < 1024; off <<= 1) {
    int v = part[t];
    int u = (t >= off) ? part[t - off] : 0;
    __syncthreads();
    part[t] = v + u;
    __syncthreads();
  }
  int run = (t == 0) ? 0 : part[t - 1];
  for (int j = 0; j < per; ++j) {
    int i = base + j;
    if (i < N) {
      rs[i] = run;
      cursor[i] = run;
      run += outdeg[i] + 1;
    }
  }
  if (t == 0) rs[N] = part[1023];
}

__global__ void k_fill(const int* s32, const int* d32, const float* dinv,
                       int* cursor, int* col, float* wgt, int E, int N) {
  int e = blockIdx.x * blockDim.x + threadIdx.x;
  if (e < E) {
    int s = s32[e], d = d32[e];
    int pos = atomicAdd(&cursor[s], 1);
    col[pos] = d;
    wgt[pos] = dinv[s] * dinv[d];
  } else if (e < E + N) {
    int i = e - E;
    int pos = atomicAdd(&cursor[i], 1);
    col[pos] = i;
    float di = dinv[i];
    wgt[pos] = di * di;
  }
}

// cast x (N*CH floats) -> bf16, zero-pad rows up to M_pad
__global__ void k_cast_x(const float* x, ushort* xb, int n4, int n4p) {
  int i = blockIdx.x * blockDim.x + threadIdx.x;
  if (i >= n4p) return;
  ushort4 o;
  if (i < n4) {
    float4 v = ((const float4*)x)[i];
    o = (ushort4){ f2b(v.x), f2b(v.y), f2b(v.z), f2b(v.w) };
  } else {
    o = (ushort4){ 0, 0, 0, 0 };
  }
  ((ushort4*)xb)[i] = o;
}

// W[k][n] (512x512) -> WT[n][k] bf16, both weights in one launch
__global__ void k_cast_wt2(const float* W1, ushort* WT1, const float* W2, ushort* WT2) {
  int idx = blockIdx.x * blockDim.x + threadIdx.x;
  if (idx >= 2 * CH * CH) return;
  const float* W = (idx < CH * CH) ? W1 : W2;
  ushort* WT = (idx < CH * CH) ? WT1 : WT2;
  int j = idx & (CH * CH - 1);
  int n = j >> 9, k = j & 511;
  WT[j] = f2b(W[(k << 9) + n]);
}

// C[M_pad,512] = A[M_pad,512](bf16) @ B(BT[n][k] bf16) + bias -> bf16 out.
// m97 structure: 128x128 tile, BK=64, global_load_lds(16B), 4 waves, 64x64/wave.
__global__ __launch_bounds__(256) void k_gemm(const ushort* __restrict__ A,
                                              const ushort* __restrict__ BT,
                                              const float* __restrict__ bias,
                                              ushort* __restrict__ Cout) {
  __shared__ __align__(16) ushort As[BM * BK];
  __shared__ __align__(16) ushort Bs[BN * BK];
  const int t = threadIdx.x;
  const int wave = t >> 6;
  const int lane = t & 63;
  const int l15 = lane & 15;
  const int lh = lane >> 4;
  const int wm = wave >> 1;   // 0..1
  const int wn = wave & 1;    // 0..1
  const int row0 = blockIdx.x * BM;
  const int col0 = blockIdx.y * BN;

  const int o0 = t * 16;           // byte offset within a 4KB issue
  f32x4 acc[4][4] = {};

  #pragma unroll 1
  for (int kt = 0; kt < CH / BK; ++kt) {
    const int k0 = kt * BK;
    #pragma unroll
    for (int i = 0; i < 4; ++i) {
      int o = i * 4096 + o0;           // linear byte offset into As/Bs
      int row = o >> 7;                // /128B per row (64 bf16)
      int cb = o & 127;
      const ushort* sa = A + (size_t)(row0 + row) * CH + k0 + (cb >> 1);
      const ushort* sb = BT + (size_t)(col0 + row) * CH + k0 + (cb >> 1);
      __builtin_amdgcn_global_load_lds(
          (const __attribute__((address_space(1))) void*)sa,
          (__attribute__((address_space(3))) void*)((char*)As + o), 16, 0, 0);
      __builtin_amdgcn_global_load_lds(
          (const __attribute__((address_space(1))) void*)sb,
          (__attribute__((address_space(3))) void*)((char*)Bs + o), 16, 0, 0);
    }
    __syncthreads();
    #pragma unroll
    for (int ks = 0; ks < 2; ++ks) {
      short8 af[4], bf[4];
      #pragma unroll
      for (int mi = 0; mi < 4; ++mi)
        af[mi] = *(const short8*)&As[(wm * 64 + mi * 16 + l15) * BK + ks * 32 + lh * 8];
      #pragma unroll
      for (int ni = 0; ni < 4; ++ni)
        bf[ni] = *(const short8*)&Bs[(wn * 64 + ni * 16 + l15) * BK + ks * 32 + lh * 8];
      #pragma unroll
      for (int mi = 0; mi < 4; ++mi)
        #pragma unroll
        for (int ni = 0; ni < 4; ++ni)
          acc[mi][ni] = __builtin_amdgcn_mfma_f32_16x16x32_bf16(af[mi], bf[ni], acc[mi][ni], 0, 0, 0);
    }
    __syncthreads();
  }

  // C/D layout: col = lane&15, row = (lane>>4)*4 + reg  (verified m89/m91)
  #pragma unroll
  for (int ni = 0; ni < 4; ++ni) {
    int c = col0 + wn * 64 + ni * 16 + l15;
    float bi = bias[c];
    #pragma unroll
    for (int mi = 0; mi < 4; ++mi) {
      int row = row0 + wm * 64 + mi * 16 + lh * 4;
      #pragma unroll
      for (int r = 0; r < 4; ++r)
        Cout[(size_t)(row + r) * CH + c] = f2b(acc[mi][ni][r] + bi);
    }
  }
}

// out[i,:] = sum_j wgt[j] * h[col[j],:]; bf16 gather (1 uint = 2 ch per thread)
__global__ __launch_bounds__(256) void k_agg_b(const ushort* __restrict__ h,
                                               const int* __restrict__ rs,
                                               const int* __restrict__ col,
                                               const float* __restrict__ wgt,
                                               ushort* __restrict__ out) {
  int i = blockIdx.x;
  int t = threadIdx.x;
  int beg = rs[i], end = rs[i + 1];
  const uint* hb = (const uint*)h;
  float a0 = 0.f, a1 = 0.f;
  for (int j = beg; j < end; ++j) {
    float w = wgt[j];
    uint u = hb[(size_t)col[j] * 256 + t];
    a0 += w * blo(u);
    a1 += w * bhi(u);
  }
  ((uint*)out)[(size_t)i * 256 + t] = (uint)f2b(a0) | ((uint)f2b(a1) << 16);
}

__global__ __launch_bounds__(256) void k_agg_f(const ushort* __restrict__ h,
                                               const int* __restrict__ rs,
                                               const int* __restrict__ col,
                                               const float* __restrict__ wgt,
                                               float* __restrict__ out) {
  int i = blockIdx.x;
  int t = threadIdx.x;
  int beg = rs[i], end = rs[i + 1];
  const uint* hb = (const uint*)h;
  float a0 = 0.f, a1 = 0.f;
  for (int j = beg; j < end; ++j) {
    float w = wgt[j];
    uint u = hb[(size_t)col[j] * 256 + t];
    a0 += w * blo(u);
    a1 += w * bhi(u);
  }
  ((float2*)out)[(size_t)i * 256 + t] = (float2){ a0, a1 };
}

__global__ __launch_bounds__(256) void k_bn_stats(const ushort* __restrict__ a,
                                                  float* __restrict__ stats, int N) {
  int t = threadIdx.x;
  const uint* ab = (const uint*)a;
  float s0 = 0.f, q0 = 0.f, s1 = 0.f, q1 = 0.f;
  for (int i = blockIdx.x; i < N; i += gridDim.x) {
    uint u = ab[(size_t)i * 256 + t];
    float lo = blo(u), hi = bhi(u);
    s0 += lo; q0 += lo * lo;
    s1 += hi; q1 += hi * hi;
  }
  atomicAdd(&stats[2 * t], s0);
  atomicAdd(&stats[2 * t + 1], s1);
  atomicAdd(&stats[CH + 2 * t], q0);
  atomicAdd(&stats[CH + 2 * t + 1], q1);
}

__global__ void k_bn_scale(const float* stats, const float* gamma, const float* beta,
                           float* scale, float* shift, float invN) {
  int c = blockIdx.x * blockDim.x + threadIdx.x;
  if (c >= CH) return;
  float mu = stats[c] * invN;
  float var = stats[CH + c] * invN - mu * mu;  // biased var, matches jnp.var
  float s = gamma[c] * rsqrtf(var + 1e-5f);
  scale[c] = s;
  shift[c] = beta[c] - s * mu;
}

// BN+ReLU on bf16 in -> bf16 out, zero-pad rows up to M_pad. nu/nup in uints.
__global__ void k_bn_apply(const ushort* __restrict__ a, const float* __restrict__ scale,
                           const float* __restrict__ shift, ushort* __restrict__ hb,
                           int nu, int nup) {
  int i = blockIdx.x * blockDim.x + threadIdx.x;
  if (i >= nup) return;
  uint o = 0;
  if (i < nu) {
    uint u = ((const uint*)a)[i];
    int cu = i & 255;
    float2 sc = ((const float2*)scale)[cu];
    float2 sh = ((const float2*)shift)[cu];
    float r0 = fmaxf(blo(u) * sc.x + sh.x, 0.f);
    float r1 = fmaxf(bhi(u) * sc.y + sh.y, 0.f);
    o = (uint)f2b(r0) | ((uint)f2b(r1) << 16);
  }
  ((uint*)hb)[i] = o;
}

extern "C" void kernel_launch(void* const* d_in, const int* in_sizes, int n_in,
                              void* d_out, int out_size, void* d_ws, size_t ws_size,
                              hipStream_t stream) {
  const float* x     = (const float*)d_in[0];
  const float* W1    = (const float*)d_in[1];
  const float* b1    = (const float*)d_in[2];
  const float* gamma = (const float*)d_in[3];
  const float* beta  = (const float*)d_in[4];
  const float* W2    = (const float*)d_in[5];
  const float* b2    = (const float*)d_in[6];
  const int*   ei    = (const int*)d_in[7];
  const int N = in_sizes[0] / CH;
  const int E = in_sizes[7] / 2;
  const int Mp = ((N + BM - 1) / BM) * BM;   // padded row count
  float* out = (float*)d_out;

  char* wsp = (char*)d_ws;
  size_t off = 0;
  auto alloc = [&](size_t b) { char* p = wsp + off; off += (b + 255) & ~(size_t)255; return p; };
  int*    outdeg = (int*)alloc((size_t)N * 4);         // zeroed below
  int*    indeg  = (int*)alloc((size_t)N * 4);         // zeroed below
  float*  stats  = (float*)alloc(1024 * 4);            // zeroed below
  float*  scale  = (float*)alloc(CH * 4);
  float*  shift  = (float*)alloc(CH * 4);
  int*    flag   = (int*)alloc(4);
  int*    s32    = (int*)alloc((size_t)E * 4);
  int*    d32    = (int*)alloc((size_t)E * 4);
  float*  dinv   = (float*)alloc((size_t)N * 4);
  int*    rs     = (int*)alloc((size_t)(N + 1) * 4);
  int*    cursor = (int*)alloc((size_t)N * 4);
  int*    colx   = (int*)alloc((size_t)(E + N) * 4);
  float*  wgt    = (float*)alloc((size_t)(E + N) * 4);
  ushort* xb     = (ushort*)alloc((size_t)Mp * CH * 2);
  ushort* w1t    = (ushort*)alloc((size_t)CH * CH * 2);
  ushort* w2t    = (ushort*)alloc((size_t)CH * CH * 2);
  ushort* h1b    = (ushort*)alloc((size_t)Mp * CH * 2);  // GEMM1 out (bf16)
  ushort* a1b    = (ushort*)alloc((size_t)N * CH * 2);   // agg1 out (bf16)
  ushort* h3b    = (ushort*)alloc((size_t)Mp * CH * 2);  // BN+ReLU out (bf16)
  ushort* h2b    = (ushort*)alloc((size_t)Mp * CH * 2);  // GEMM2 out (bf16)

  // zero the contiguous [outdeg .. stats] span
  int zn = (int)(((char*)stats - (char*)outdeg) / 4) + 1024;
  k_zero<<<dim3((zn + 255) / 256), dim3(256), 0, stream>>>(outdeg, zn);
  k_detect<<<1, 1, 0, stream>>>(ei, flag);
  int eb = (E + 255) / 256;
  k_cvt_count<<<eb, 256, 0, stream>>>(ei, flag, s32, d32, outdeg, indeg, E);
  k_dinv<<<(N + 255) / 256, 256, 0, stream>>>(indeg, dinv, N);
  k_scan<<<1, 1024, 0, stream>>>(outdeg, rs, cursor, N);
  k_fill<<<(E + N + 255) / 256, 256, 0, stream>>>(s32, d32, dinv, cursor, colx, wgt, E, N);
  int n4 = N * CH / 4, n4p = Mp * CH / 4;
  k_cast_x<<<(n4p + 255) / 256, 256, 0, stream>>>(x, xb, n4, n4p);
  k_cast_wt2<<<(2 * CH * CH + 255) / 256, 256, 0, stream>>>(W1, w1t, W2, w2t);
  dim3 gg(Mp / BM, CH / BN);
  k_gemm<<<gg, 256, 0, stream>>>(xb, w1t, b1, h1b);
  k_agg_b<<<N, 256, 0, stream>>>(h1b, rs, colx, wgt, a1b);
  k_bn_stats<<<256, 256, 0, stream>>>(a1b, stats, N);
  k_bn_scale<<<2, 256, 0, stream>>>(stats, gamma, beta, scale, shift, 1.0f / (float)N);
  int nu = N * CH / 2, nup = Mp * CH / 2;
  k_bn_apply<<<(nup + 255) / 256, 256, 0, stream>>>(a1b, scale, shift, h3b, nu, nup);
  k_gemm<<<gg, 256, 0, stream>>>(h3b, w2t, b2, h2b);
  k_agg_f<<<N, 256, 0, stream>>>(h2b, rs, colx, wgt, out);
}

// Round 4
// 181.981 us; speedup vs baseline: 1.6054x; 1.1625x over previous
//
#include <hip/hip_runtime.h>
#include <hip/hip_bf16.h>

#define CH 512
#define BM 128
#define BN 128
#define BK 64

typedef __attribute__((ext_vector_type(8))) short short8;
typedef __attribute__((ext_vector_type(4))) float f32x4;

static __device__ __forceinline__ ushort f2b(float f) {
  union { __hip_bfloat16 b; ushort u; } c;
  c.b = __float2bfloat16(f);
  return c.u;
}
static __device__ __forceinline__ float blo(uint u) { return __uint_as_float(u << 16); }
static __device__ __forceinline__ float bhi(uint u) { return __uint_as_float(u & 0xffff0000u); }
static __device__ __forceinline__ uint pk2(float a, float b) {
  return (uint)f2b(a) | ((uint)f2b(b) << 16);
}

__global__ void k_zero(int* p, int n) {
  int i = blockIdx.x * blockDim.x + threadIdx.x;
  if (i < n) p[i] = 0;
}

// Detect whether edge_index was passed as int64 (odd int32 words == 0) or int32.
__global__ void k_detect(const int* ei, int* flag) {
  if (threadIdx.x == 0 && blockIdx.x == 0) {
    int zeros = 0;
    for (int j = 1; j < 32; j += 2) zeros += (ei[j] == 0) ? 1 : 0;
    *flag = (zeros >= 14) ? 1 : 0;
  }
}

__global__ void k_cvt_count(const int* ei, const int* flag, int* s32, int* d32,
                            int* outdeg, int* indeg, int E) {
  int e = blockIdx.x * blockDim.x + threadIdx.x;
  if (e >= E) return;
  int s, d;
  if (*flag) {
    const long long* p = (const long long*)ei;
    s = (int)p[e];
    d = (int)p[e + E];
  } else {
    s = ei[e];
    d = ei[e + E];
  }
  s32[e] = s;
  d32[e] = d;
  atomicAdd(&outdeg[s], 1);
  atomicAdd(&indeg[d], 1);
}

__global__ void k_dinv(const int* indeg, float* dinv, int N) {
  int i = blockIdx.x * blockDim.x + threadIdx.x;
  if (i < N) dinv[i] = rsqrtf((float)(indeg[i] + 1));  // +1 self loop; always > 0
}

__global__ __launch_bounds__(1024) void k_scan(const int* outdeg, int* rs, int* cursor, int N) {
  __shared__ int part[1024];
  int t = threadIdx.x;
  int per = (N + 1023) >> 10;
  int base = t * per;
  int s = 0;
  for (int j = 0; j < per; ++j) {
    int i = base + j;
    if (i < N) s += outdeg[i] + 1;  // +1 self loop
  }
  part[t] = s;
  __syncthreads();
  for (int off = 1; off < 1024; off <<= 1) {
    int v = part[t];
    int u = (t >= off) ? part[t - off] : 0;
    __syncthreads();
    part[t] = v + u;
    __syncthreads();
  }
  int run = (t == 0) ? 0 : part[t - 1];
  for (int j = 0; j < per; ++j) {
    int i = base + j;
    if (i < N) {
      rs[i] = run;
      cursor[i] = run;
      run += outdeg[i] + 1;
    }
  }
  if (t == 0) rs[N] = part[1023];
}

__global__ void k_fill(const int* s32, const int* d32, const float* dinv,
                       int* cursor, int* col, float* wgt, int E, int N) {
  int e = blockIdx.x * blockDim.x + threadIdx.x;
  if (e < E) {
    int s = s32[e], d = d32[e];
    int pos = atomicAdd(&cursor[s], 1);
    col[pos] = d;
    wgt[pos] = dinv[s] * dinv[d];
  } else if (e < E + N) {
    int i = e - E;
    int pos = atomicAdd(&cursor[i], 1);
    col[pos] = i;
    float di = dinv[i];
    wgt[pos] = di * di;
  }
}

// cast x (N*CH floats) -> bf16, zero-pad rows up to M_pad
__global__ void k_cast_x(const float* x, ushort* xb, int n4, int n4p) {
  int i = blockIdx.x * blockDim.x + threadIdx.x;
  if (i >= n4p) return;
  ushort4 o;
  if (i < n4) {
    float4 v = ((const float4*)x)[i];
    o = (ushort4){ f2b(v.x), f2b(v.y), f2b(v.z), f2b(v.w) };
  } else {
    o = (ushort4){ 0, 0, 0, 0 };
  }
  ((ushort4*)xb)[i] = o;
}

// W[k][n] (512x512) -> WT[n][k] bf16, both weights in one launch
__global__ void k_cast_wt2(const float* W1, ushort* WT1, const float* W2, ushort* WT2) {
  int idx = blockIdx.x * blockDim.x + threadIdx.x;
  if (idx >= 2 * CH * CH) return;
  const float* W = (idx < CH * CH) ? W1 : W2;
  ushort* WT = (idx < CH * CH) ? WT1 : WT2;
  int j = idx & (CH * CH - 1);
  int n = j >> 9, k = j & 511;
  WT[j] = f2b(W[(k << 9) + n]);
}

// C[M_pad,512] = A[M_pad,512](bf16) @ B(BT[n][k] bf16) + bias -> bf16 out.
// m97 structure: 128x128 tile, BK=64, global_load_lds(16B), 4 waves, 64x64/wave.
__global__ __launch_bounds__(256) void k_gemm(const ushort* __restrict__ A,
                                              const ushort* __restrict__ BT,
                                              const float* __restrict__ bias,
                                              ushort* __restrict__ Cout) {
  __shared__ __align__(16) ushort As[BM * BK];
  __shared__ __align__(16) ushort Bs[BN * BK];
  const int t = threadIdx.x;
  const int wave = t >> 6;
  const int lane = t & 63;
  const int l15 = lane & 15;
  const int lh = lane >> 4;
  const int wm = wave >> 1;   // 0..1
  const int wn = wave & 1;    // 0..1
  const int row0 = blockIdx.x * BM;
  const int col0 = blockIdx.y * BN;

  const int o0 = t * 16;           // byte offset within a 4KB issue
  f32x4 acc[4][4] = {};

  #pragma unroll 1
  for (int kt = 0; kt < CH / BK; ++kt) {
    const int k0 = kt * BK;
    #pragma unroll
    for (int i = 0; i < 4; ++i) {
      int o = i * 4096 + o0;           // linear byte offset into As/Bs
      int row = o >> 7;                // /128B per row (64 bf16)
      int cb = o & 127;
      const ushort* sa = A + (size_t)(row0 + row) * CH + k0 + (cb >> 1);
      const ushort* sb = BT + (size_t)(col0 + row) * CH + k0 + (cb >> 1);
      __builtin_amdgcn_global_load_lds(
          (const __attribute__((address_space(1))) void*)sa,
          (__attribute__((address_space(3))) void*)((char*)As + o), 16, 0, 0);
      __builtin_amdgcn_global_load_lds(
          (const __attribute__((address_space(1))) void*)sb,
          (__attribute__((address_space(3))) void*)((char*)Bs + o), 16, 0, 0);
    }
    __syncthreads();
    #pragma unroll
    for (int ks = 0; ks < 2; ++ks) {
      short8 af[4], bf[4];
      #pragma unroll
      for (int mi = 0; mi < 4; ++mi)
        af[mi] = *(const short8*)&As[(wm * 64 + mi * 16 + l15) * BK + ks * 32 + lh * 8];
      #pragma unroll
      for (int ni = 0; ni < 4; ++ni)
        bf[ni] = *(const short8*)&Bs[(wn * 64 + ni * 16 + l15) * BK + ks * 32 + lh * 8];
      #pragma unroll
      for (int mi = 0; mi < 4; ++mi)
        #pragma unroll
        for (int ni = 0; ni < 4; ++ni)
          acc[mi][ni] = __builtin_amdgcn_mfma_f32_16x16x32_bf16(af[mi], bf[ni], acc[mi][ni], 0, 0, 0);
    }
    __syncthreads();
  }

  // C/D layout: col = lane&15, row = (lane>>4)*4 + reg  (verified m89/m91)
  #pragma unroll
  for (int ni = 0; ni < 4; ++ni) {
    int c = col0 + wn * 64 + ni * 16 + l15;
    float bi = bias[c];
    #pragma unroll
    for (int mi = 0; mi < 4; ++mi) {
      int row = row0 + wm * 64 + mi * 16 + lh * 4;
      #pragma unroll
      for (int r = 0; r < 4; ++r)
        Cout[(size_t)(row + r) * CH + c] = f2b(acc[mi][ni][r] + bi);
    }
  }
}

// Wave-per-node agg: out[i,:] = sum_j wgt[j] * h[col[j],:]
// col/wgt preloaded 1/lane + __shfl broadcast; 16B (uint4) gather per lane.
// Lane l owns channels 8l..8l+7. TMPL: OUTF=1 -> f32 out, else bf16 out.
template <int OUTF>
__global__ __launch_bounds__(256) void k_agg_w(const ushort* __restrict__ h,
                                               const int* __restrict__ rs,
                                               const int* __restrict__ col,
                                               const float* __restrict__ wgt,
                                               void* __restrict__ out, int N) {
  int wv = (blockIdx.x << 2) + (threadIdx.x >> 6);
  if (wv >= N) return;
  int lane = threadIdx.x & 63;
  int beg = rs[wv], end = rs[wv + 1];
  const uint4* hb = (const uint4*)h;
  float a0 = 0.f, a1 = 0.f, a2 = 0.f, a3 = 0.f, a4 = 0.f, a5 = 0.f, a6 = 0.f, a7 = 0.f;
  for (int base = beg; base < end; base += 64) {
    int j = base + lane;
    int cl = 0;
    float wl = 0.f;
    if (j < end) { cl = col[j]; wl = wgt[j]; }
    int cnt = min(64, end - base);
    for (int jj = 0; jj < cnt; ++jj) {
      int c = __shfl(cl, jj);
      float w = __shfl(wl, jj);
      uint4 u = hb[(size_t)c * 64 + lane];
      a0 += w * blo(u.x); a1 += w * bhi(u.x);
      a2 += w * blo(u.y); a3 += w * bhi(u.y);
      a4 += w * blo(u.z); a5 += w * bhi(u.z);
      a6 += w * blo(u.w); a7 += w * bhi(u.w);
    }
  }
  if (OUTF) {
    float4* o = (float4*)out;
    o[(size_t)wv * 128 + lane * 2]     = (float4){ a0, a1, a2, a3 };
    o[(size_t)wv * 128 + lane * 2 + 1] = (float4){ a4, a5, a6, a7 };
  } else {
    uint4 o = { pk2(a0, a1), pk2(a2, a3), pk2(a4, a5), pk2(a6, a7) };
    ((uint4*)out)[(size_t)wv * 64 + lane] = o;
  }
}

__global__ __launch_bounds__(256) void k_bn_stats(const ushort* __restrict__ a,
                                                  float* __restrict__ stats, int N) {
  int t = threadIdx.x;
  const uint* ab = (const uint*)a;
  float s0 = 0.f, q0 = 0.f, s1 = 0.f, q1 = 0.f;
  for (int i = blockIdx.x; i < N; i += gridDim.x) {
    uint u = ab[(size_t)i * 256 + t];
    float lo = blo(u), hi = bhi(u);
    s0 += lo; q0 += lo * lo;
    s1 += hi; q1 += hi * hi;
  }
  atomicAdd(&stats[2 * t], s0);
  atomicAdd(&stats[2 * t + 1], s1);
  atomicAdd(&stats[CH + 2 * t], q0);
  atomicAdd(&stats[CH + 2 * t + 1], q1);
}

__global__ void k_bn_scale(const float* stats, const float* gamma, const float* beta,
                           float* scale, float* shift, float invN) {
  int c = blockIdx.x * blockDim.x + threadIdx.x;
  if (c >= CH) return;
  float mu = stats[c] * invN;
  float var = stats[CH + c] * invN - mu * mu;  // biased var, matches jnp.var
  float s = gamma[c] * rsqrtf(var + 1e-5f);
  scale[c] = s;
  shift[c] = beta[c] - s * mu;
}

// BN+ReLU on bf16 in -> bf16 out, zero-pad rows up to M_pad. nu/nup in uints.
__global__ void k_bn_apply(const ushort* __restrict__ a, const float* __restrict__ scale,
                           const float* __restrict__ shift, ushort* __restrict__ hb,
                           int nu, int nup) {
  int i = blockIdx.x * blockDim.x + threadIdx.x;
  if (i >= nup) return;
  uint o = 0;
  if (i < nu) {
    uint u = ((const uint*)a)[i];
    int cu = i & 255;
    float2 sc = ((const float2*)scale)[cu];
    float2 sh = ((const float2*)shift)[cu];
    float r0 = fmaxf(blo(u) * sc.x + sh.x, 0.f);
    float r1 = fmaxf(bhi(u) * sc.y + sh.y, 0.f);
    o = (uint)f2b(r0) | ((uint)f2b(r1) << 16);
  }
  ((uint*)hb)[i] = o;
}

extern "C" void kernel_launch(void* const* d_in, const int* in_sizes, int n_in,
                              void* d_out, int out_size, void* d_ws, size_t ws_size,
                              hipStream_t stream) {
  const float* x     = (const float*)d_in[0];
  const float* W1    = (const float*)d_in[1];
  const float* b1    = (const float*)d_in[2];
  const float* gamma = (const float*)d_in[3];
  const float* beta  = (const float*)d_in[4];
  const float* W2    = (const float*)d_in[5];
  const float* b2    = (const float*)d_in[6];
  const int*   ei    = (const int*)d_in[7];
  const int N = in_sizes[0] / CH;
  const int E = in_sizes[7] / 2;
  const int Mp = ((N + BM - 1) / BM) * BM;   // padded row count
  float* out = (float*)d_out;

  char* wsp = (char*)d_ws;
  size_t off = 0;
  auto alloc = [&](size_t b) { char* p = wsp + off; off += (b + 255) & ~(size_t)255; return p; };
  int*    outdeg = (int*)alloc((size_t)N * 4);         // zeroed below
  int*    indeg  = (int*)alloc((size_t)N * 4);         // zeroed below
  float*  stats  = (float*)alloc(1024 * 4);            // zeroed below
  float*  scale  = (float*)alloc(CH * 4);
  float*  shift  = (float*)alloc(CH * 4);
  int*    flag   = (int*)alloc(4);
  int*    s32    = (int*)alloc((size_t)E * 4);
  int*    d32    = (int*)alloc((size_t)E * 4);
  float*  dinv   = (float*)alloc((size_t)N * 4);
  int*    rs     = (int*)alloc((size_t)(N + 1) * 4);
  int*    cursor = (int*)alloc((size_t)N * 4);
  int*    colx   = (int*)alloc((size_t)(E + N) * 4);
  float*  wgt    = (float*)alloc((size_t)(E + N) * 4);
  ushort* xb     = (ushort*)alloc((size_t)Mp * CH * 2);
  ushort* w1t    = (ushort*)alloc((size_t)CH * CH * 2);
  ushort* w2t    = (ushort*)alloc((size_t)CH * CH * 2);
  ushort* h1b    = (ushort*)alloc((size_t)Mp * CH * 2);  // GEMM1 out (bf16)
  ushort* a1b    = (ushort*)alloc((size_t)N * CH * 2);   // agg1 out (bf16)
  ushort* h3b    = (ushort*)alloc((size_t)Mp * CH * 2);  // BN+ReLU out (bf16)
  ushort* h2b    = (ushort*)alloc((size_t)Mp * CH * 2);  // GEMM2 out (bf16)

  // zero the contiguous [outdeg .. stats] span
  int zn = (int)(((char*)stats - (char*)outdeg) / 4) + 1024;
  k_zero<<<dim3((zn + 255) / 256), dim3(256), 0, stream>>>(outdeg, zn);
  k_detect<<<1, 1, 0, stream>>>(ei, flag);
  int eb = (E + 255) / 256;
  k_cvt_count<<<eb, 256, 0, stream>>>(ei, flag, s32, d32, outdeg, indeg, E);
  k_dinv<<<(N + 255) / 256, 256, 0, stream>>>(indeg, dinv, N);
  k_scan<<<1, 1024, 0, stream>>>(outdeg, rs, cursor, N);
  k_fill<<<(E + N + 255) / 256, 256, 0, stream>>>(s32, d32, dinv, cursor, colx, wgt, E, N);
  int n4 = N * CH / 4, n4p = Mp * CH / 4;
  k_cast_x<<<(n4p + 255) / 256, 256, 0, stream>>>(x, xb, n4, n4p);
  k_cast_wt2<<<(2 * CH * CH + 255) / 256, 256, 0, stream>>>(W1, w1t, W2, w2t);
  dim3 gg(Mp / BM, CH / BN);
  int ab = (N + 3) / 4;
  k_gemm<<<gg, 256, 0, stream>>>(xb, w1t, b1, h1b);
  k_agg_w<0><<<ab, 256, 0, stream>>>(h1b, rs, colx, wgt, a1b, N);
  k_bn_stats<<<256, 256, 0, stream>>>(a1b, stats, N);
  k_bn_scale<<<2, 256, 0, stream>>>(stats, gamma, beta, scale, shift, 1.0f / (float)N);
  int nu = N * CH / 2, nup = Mp * CH / 2;
  k_bn_apply<<<(nup + 255) / 256, 256, 0, stream>>>(a1b, scale, shift, h3b, nu, nup);
  k_gemm<<<gg, 256, 0, stream>>>(h3b, w2t, b2, h2b);
  k_agg_w<1><<<ab, 256, 0, stream>>>(h2b, rs, colx, wgt, out, N);
}

// Round 5
// 178.348 us; speedup vs baseline: 1.6381x; 1.0204x over previous
//
#include <hip/hip_runtime.h>
#include <hip/hip_bf16.h>

#define CH 512
#define BM 128
#define BN 64
#define BK 64
#define NT (CH / BK)

typedef __attribute__((ext_vector_type(8))) short short8;
typedef __attribute__((ext_vector_type(4))) float f32x4;

static __device__ __forceinline__ ushort f2b(float f) {
  union { __hip_bfloat16 b; ushort u; } c;
  c.b = __float2bfloat16(f);
  return c.u;
}
static __device__ __forceinline__ float blo(uint u) { return __uint_as_float(u << 16); }
static __device__ __forceinline__ float bhi(uint u) { return __uint_as_float(u & 0xffff0000u); }
static __device__ __forceinline__ uint pk2(float a, float b) {
  return (uint)f2b(a) | ((uint)f2b(b) << 16);
}

// zero p[0..n) + edge-dtype detect (int64 vs int32) in one launch
__global__ void k_zero_detect(int* p, int n, const int* ei, int* flag) {
  int i = blockIdx.x * blockDim.x + threadIdx.x;
  if (i < n) p[i] = 0;
  if (i == 0) {
    int zeros = 0;
    for (int j = 1; j < 32; j += 2) zeros += (ei[j] == 0) ? 1 : 0;
    *flag = (zeros >= 14) ? 1 : 0;
  }
}

__global__ void k_cvt_count(const int* ei, const int* flag, int* s32, int* d32,
                            int* outdeg, int* indeg, int E) {
  int e = blockIdx.x * blockDim.x + threadIdx.x;
  if (e >= E) return;
  int s, d;
  if (*flag) {
    const long long* p = (const long long*)ei;
    s = (int)p[e];
    d = (int)p[e + E];
  } else {
    s = ei[e];
    d = ei[e + E];
  }
  s32[e] = s;
  d32[e] = d;
  atomicAdd(&outdeg[s], 1);
  atomicAdd(&indeg[d], 1);
}

// dinv + exclusive scan of (outdeg+1) in one launch
__global__ __launch_bounds__(1024) void k_scan(const int* outdeg, const int* indeg,
                                               float* dinv, int* rs, int* cursor, int N) {
  __shared__ int part[1024];
  int t = threadIdx.x;
  for (int i = t; i < N; i += 1024) dinv[i] = rsqrtf((float)(indeg[i] + 1));
  int per = (N + 1023) >> 10;
  int base = t * per;
  int s = 0;
  for (int j = 0; j < per; ++j) {
    int i = base + j;
    if (i < N) s += outdeg[i] + 1;  // +1 self loop
  }
  part[t] = s;
  __syncthreads();
  for (int off = 1; off < 1024; off <<= 1) {
    int v = part[t];
    int u = (t >= off) ? part[t - off] : 0;
    __syncthreads();
    part[t] = v + u;
    __syncthreads();
  }
  int run = (t == 0) ? 0 : part[t - 1];
  for (int j = 0; j < per; ++j) {
    int i = base + j;
    if (i < N) {
      rs[i] = run;
      cursor[i] = run;
      run += outdeg[i] + 1;
    }
  }
  if (t == 0) rs[N] = part[1023];
}

__global__ void k_fill(const int* s32, const int* d32, const float* dinv,
                       int* cursor, int* col, float* wgt, int E, int N) {
  int e = blockIdx.x * blockDim.x + threadIdx.x;
  if (e < E) {
    int s = s32[e], d = d32[e];
    int pos = atomicAdd(&cursor[s], 1);
    col[pos] = d;
    wgt[pos] = dinv[s] * dinv[d];
  } else if (e < E + N) {
    int i = e - E;
    int pos = atomicAdd(&cursor[i], 1);
    col[pos] = i;
    float di = dinv[i];
    wgt[pos] = di * di;
  }
}

// cast x (N*CH floats) -> bf16, zero-pad rows up to M_pad
__global__ void k_cast_x(const float* x, ushort* xb, int n4, int n4p) {
  int i = blockIdx.x * blockDim.x + threadIdx.x;
  if (i >= n4p) return;
  ushort4 o;
  if (i < n4) {
    float4 v = ((const float4*)x)[i];
    o = (ushort4){ f2b(v.x), f2b(v.y), f2b(v.z), f2b(v.w) };
  } else {
    o = (ushort4){ 0, 0, 0, 0 };
  }
  ((ushort4*)xb)[i] = o;
}

// W[k][n] (512x512) -> WT[n][k] bf16, both weights in one launch
__global__ void k_cast_wt2(const float* W1, ushort* WT1, const float* W2, ushort* WT2) {
  int idx = blockIdx.x * blockDim.x + threadIdx.x;
  if (idx >= 2 * CH * CH) return;
  const float* W = (idx < CH * CH) ? W1 : W2;
  ushort* WT = (idx < CH * CH) ? WT1 : WT2;
  int j = idx & (CH * CH - 1);
  int n = j >> 9, k = j & 511;
  WT[j] = f2b(W[(k << 9) + n]);
}

// C[M_pad,512] = A[M_pad,512](bf16) @ B(BT[n][k]) + bias -> bf16.
// BM=128 BN=64 BK=64, 632 blocks (1D, XCD chunk-swizzled), 4 waves (2M x 2N),
// wave-tile 64x32. Double-buffered LDS, T3-min pipeline: STAGE(next) ->
// compute(cur) -> vmcnt(0) -> raw s_barrier (one barrier per K-tile).
__global__ __launch_bounds__(256) void k_gemm(const ushort* __restrict__ A,
                                              const ushort* __restrict__ BT,
                                              const float* __restrict__ bias,
                                              ushort* __restrict__ Cout, int gy) {
  __shared__ __align__(16) ushort As[2][BM * BK];
  __shared__ __align__(16) ushort Bs[2][BN * BK];
  const int t = threadIdx.x;
  const int wave = t >> 6;
  const int lane = t & 63;
  const int l15 = lane & 15;
  const int lh = lane >> 4;
  const int wm = wave >> 1;   // 0..1 (M half)
  const int wn = wave & 1;    // 0..1 (N half)

  // bijective XCD chunk swizzle (m204): consecutive L share the A-panel (bx)
  int nwg = gridDim.x, wg = blockIdx.x;
  int xcd = wg & 7, i8 = wg >> 3;
  int q = nwg >> 3, r = nwg & 7;
  int L = ((xcd < r) ? xcd * (q + 1) : r * (q + 1) + (xcd - r) * q) + i8;
  int bx = L / gy, by = L % gy;
  const int row0 = bx * BM;
  const int col0 = by * BN;

  f32x4 acc[4][2] = {};

  auto STAGE = [&](int buf, int kt) {
    const int k0 = kt * BK;
    #pragma unroll
    for (int i = 0; i < 4; ++i) {                 // A: 16KB = 4 x 4KB
      int o = i * 4096 + t * 16;
      int row = o >> 7, cb = o & 127;
      const ushort* sa = A + (size_t)(row0 + row) * CH + k0 + (cb >> 1);
      __builtin_amdgcn_global_load_lds(
          (const __attribute__((address_space(1))) void*)sa,
          (__attribute__((address_space(3))) void*)((char*)As[buf] + o), 16, 0, 0);
    }
    #pragma unroll
    for (int i = 0; i < 2; ++i) {                 // B: 8KB = 2 x 4KB
      int o = i * 4096 + t * 16;
      int row = o >> 7, cb = o & 127;
      const ushort* sb = BT + (size_t)(col0 + row) * CH + k0 + (cb >> 1);
      __builtin_amdgcn_global_load_lds(
          (const __attribute__((address_space(1))) void*)sb,
          (__attribute__((address_space(3))) void*)((char*)Bs[buf] + o), 16, 0, 0);
    }
  };

  STAGE(0, 0);
  asm volatile("s_waitcnt vmcnt(0)" ::: "memory");
  __builtin_amdgcn_s_barrier();

  #pragma unroll 2
  for (int kt = 0; kt < NT; ++kt) {
    int cur = kt & 1;
    if (kt + 1 < NT) STAGE(cur ^ 1, kt + 1);
    #pragma unroll
    for (int ks = 0; ks < 2; ++ks) {
      short8 af[4], bfr[2];
      #pragma unroll
      for (int mi = 0; mi < 4; ++mi)
        af[mi] = *(const short8*)&As[cur][(wm * 64 + mi * 16 + l15) * BK + ks * 32 + lh * 8];
      #pragma unroll
      for (int ni = 0; ni < 2; ++ni)
        bfr[ni] = *(const short8*)&Bs[cur][(wn * 32 + ni * 16 + l15) * BK + ks * 32 + lh * 8];
      #pragma unroll
      for (int mi = 0; mi < 4; ++mi)
        #pragma unroll
        for (int ni = 0; ni < 2; ++ni)
          acc[mi][ni] = __builtin_amdgcn_mfma_f32_16x16x32_bf16(af[mi], bfr[ni], acc[mi][ni], 0, 0, 0);
    }
    asm volatile("s_waitcnt vmcnt(0)" ::: "memory");
    __builtin_amdgcn_s_barrier();
  }

  // C/D layout: col = lane&15, row = (lane>>4)*4 + reg  (verified m89/m91)
  #pragma unroll
  for (int ni = 0; ni < 2; ++ni) {
    int c = col0 + wn * 32 + ni * 16 + l15;
    float bi = bias[c];
    #pragma unroll
    for (int mi = 0; mi < 4; ++mi) {
      int row = row0 + wm * 64 + mi * 16 + lh * 4;
      #pragma unroll
      for (int r = 0; r < 4; ++r)
        Cout[(size_t)(row + r) * CH + c] = f2b(acc[mi][ni][r] + bi);
    }
  }
}

// Wave-per-node agg: out[i,:] = sum_j wgt[j] * h[col[j],:]
// col/wgt preloaded 1/lane + __shfl broadcast; 16B (uint4) gather per lane.
template <int OUTF>
__global__ __launch_bounds__(256) void k_agg_w(const ushort* __restrict__ h,
                                               const int* __restrict__ rs,
                                               const int* __restrict__ col,
                                               const float* __restrict__ wgt,
                                               void* __restrict__ out, int N) {
  int wv = (blockIdx.x << 2) + (threadIdx.x >> 6);
  if (wv >= N) return;
  int lane = threadIdx.x & 63;
  int beg = rs[wv], end = rs[wv + 1];
  const uint4* hb = (const uint4*)h;
  float a0 = 0.f, a1 = 0.f, a2 = 0.f, a3 = 0.f, a4 = 0.f, a5 = 0.f, a6 = 0.f, a7 = 0.f;
  for (int base = beg; base < end; base += 64) {
    int j = base + lane;
    int cl = 0;
    float wl = 0.f;
    if (j < end) { cl = col[j]; wl = wgt[j]; }
    int cnt = min(64, end - base);
    for (int jj = 0; jj < cnt; ++jj) {
      int c = __shfl(cl, jj);
      float w = __shfl(wl, jj);
      uint4 u = hb[(size_t)c * 64 + lane];
      a0 += w * blo(u.x); a1 += w * bhi(u.x);
      a2 += w * blo(u.y); a3 += w * bhi(u.y);
      a4 += w * blo(u.z); a5 += w * bhi(u.z);
      a6 += w * blo(u.w); a7 += w * bhi(u.w);
    }
  }
  if (OUTF) {
    float4* o = (float4*)out;
    o[(size_t)wv * 128 + lane * 2]     = (float4){ a0, a1, a2, a3 };
    o[(size_t)wv * 128 + lane * 2 + 1] = (float4){ a4, a5, a6, a7 };
  } else {
    uint4 o = { pk2(a0, a1), pk2(a2, a3), pk2(a4, a5), pk2(a6, a7) };
    ((uint4*)out)[(size_t)wv * 64 + lane] = o;
  }
}

__global__ __launch_bounds__(256) void k_bn_stats(const ushort* __restrict__ a,
                                                  float* __restrict__ stats, int N) {
  int t = threadIdx.x;
  const uint* ab = (const uint*)a;
  float s0 = 0.f, q0 = 0.f, s1 = 0.f, q1 = 0.f;
  for (int i = blockIdx.x; i < N; i += gridDim.x) {
    uint u = ab[(size_t)i * 256 + t];
    float lo = blo(u), hi = bhi(u);
    s0 += lo; q0 += lo * lo;
    s1 += hi; q1 += hi * hi;
  }
  atomicAdd(&stats[2 * t], s0);
  atomicAdd(&stats[2 * t + 1], s1);
  atomicAdd(&stats[CH + 2 * t], q0);
  atomicAdd(&stats[CH + 2 * t + 1], q1);
}

__global__ void k_bn_scale(const float* stats, const float* gamma, const float* beta,
                           float* scale, float* shift, float invN) {
  int c = blockIdx.x * blockDim.x + threadIdx.x;
  if (c >= CH) return;
  float mu = stats[c] * invN;
  float var = stats[CH + c] * invN - mu * mu;  // biased var, matches jnp.var
  float s = gamma[c] * rsqrtf(var + 1e-5f);
  scale[c] = s;
  shift[c] = beta[c] - s * mu;
}

// BN+ReLU on bf16 in -> bf16 out, zero-pad rows up to M_pad. nu/nup in uints.
__global__ void k_bn_apply(const ushort* __restrict__ a, const float* __restrict__ scale,
                           const float* __restrict__ shift, ushort* __restrict__ hb,
                           int nu, int nup) {
  int i = blockIdx.x * blockDim.x + threadIdx.x;
  if (i >= nup) return;
  uint o = 0;
  if (i < nu) {
    uint u = ((const uint*)a)[i];
    int cu = i & 255;
    float2 sc = ((const float2*)scale)[cu];
    float2 sh = ((const float2*)shift)[cu];
    float r0 = fmaxf(blo(u) * sc.x + sh.x, 0.f);
    float r1 = fmaxf(bhi(u) * sc.y + sh.y, 0.f);
    o = (uint)f2b(r0) | ((uint)f2b(r1) << 16);
  }
  ((uint*)hb)[i] = o;
}

extern "C" void kernel_launch(void* const* d_in, const int* in_sizes, int n_in,
                              void* d_out, int out_size, void* d_ws, size_t ws_size,
                              hipStream_t stream) {
  const float* x     = (const float*)d_in[0];
  const float* W1    = (const float*)d_in[1];
  const float* b1    = (const float*)d_in[2];
  const float* gamma = (const float*)d_in[3];
  const float* beta  = (const float*)d_in[4];
  const float* W2    = (const float*)d_in[5];
  const float* b2    = (const float*)d_in[6];
  const int*   ei    = (const int*)d_in[7];
  const int N = in_sizes[0] / CH;
  const int E = in_sizes[7] / 2;
  const int Mp = ((N + BM - 1) / BM) * BM;   // padded row count
  float* out = (float*)d_out;

  char* wsp = (char*)d_ws;
  size_t off = 0;
  auto alloc = [&](size_t b) { char* p = wsp + off; off += (b + 255) & ~(size_t)255; return p; };
  int*    outdeg = (int*)alloc((size_t)N * 4);         // zeroed below
  int*    indeg  = (int*)alloc((size_t)N * 4);         // zeroed below
  float*  stats  = (float*)alloc(1024 * 4);            // zeroed below
  float*  scale  = (float*)alloc(CH * 4);
  float*  shift  = (float*)alloc(CH * 4);
  int*    flag   = (int*)alloc(4);
  int*    s32    = (int*)alloc((size_t)E * 4);
  int*    d32    = (int*)alloc((size_t)E * 4);
  float*  dinv   = (float*)alloc((size_t)N * 4);
  int*    rs     = (int*)alloc((size_t)(N + 1) * 4);
  int*    cursor = (int*)alloc((size_t)N * 4);
  int*    colx   = (int*)alloc((size_t)(E + N) * 4);
  float*  wgt    = (float*)alloc((size_t)(E + N) * 4);
  ushort* xb     = (ushort*)alloc((size_t)Mp * CH * 2);
  ushort* w1t    = (ushort*)alloc((size_t)CH * CH * 2);
  ushort* w2t    = (ushort*)alloc((size_t)CH * CH * 2);
  ushort* h1b    = (ushort*)alloc((size_t)Mp * CH * 2);  // GEMM1 out (bf16)
  ushort* a1b    = (ushort*)alloc((size_t)N * CH * 2);   // agg1 out (bf16)
  ushort* h3b    = (ushort*)alloc((size_t)Mp * CH * 2);  // BN+ReLU out (bf16)
  ushort* h2b    = (ushort*)alloc((size_t)Mp * CH * 2);  // GEMM2 out (bf16)

  // zero the contiguous [outdeg .. stats] span (+ edge dtype detect)
  int zn = (int)(((char*)stats - (char*)outdeg) / 4) + 1024;
  k_zero_detect<<<dim3((zn + 255) / 256), dim3(256), 0, stream>>>(outdeg, zn, ei, flag);
  int eb = (E + 255) / 256;
  k_cvt_count<<<eb, 256, 0, stream>>>(ei, flag, s32, d32, outdeg, indeg, E);
  k_scan<<<1, 1024, 0, stream>>>(outdeg, indeg, dinv, rs, cursor, N);
  k_fill<<<(E + N + 255) / 256, 256, 0, stream>>>(s32, d32, dinv, cursor, colx, wgt, E, N);
  int n4 = N * CH / 4, n4p = Mp * CH / 4;
  k_cast_x<<<(n4p + 255) / 256, 256, 0, stream>>>(x, xb, n4, n4p);
  k_cast_wt2<<<(2 * CH * CH + 255) / 256, 256, 0, stream>>>(W1, w1t, W2, w2t);
  int gy = CH / BN;
  int ngemm = (Mp / BM) * gy;
  int ab = (N + 3) / 4;
  k_gemm<<<ngemm, 256, 0, stream>>>(xb, w1t, b1, h1b, gy);
  k_agg_w<0><<<ab, 256, 0, stream>>>(h1b, rs, colx, wgt, a1b, N);
  k_bn_stats<<<256, 256, 0, stream>>>(a1b, stats, N);
  k_bn_scale<<<2, 256, 0, stream>>>(stats, gamma, beta, scale, shift, 1.0f / (float)N);
  int nu = N * CH / 2, nup = Mp * CH / 2;
  k_bn_apply<<<(nup + 255) / 256, 256, 0, stream>>>(a1b, scale, shift, h3b, nu, nup);
  k_gemm<<<ngemm, 256, 0, stream>>>(h3b, w2t, b2, h2b, gy);
  k_agg_w<1><<<ab, 256, 0, stream>>>(h2b, rs, colx, wgt, out, N);
}

// Round 6
// 173.081 us; speedup vs baseline: 1.6879x; 1.0304x over previous
//
#include <hip/hip_runtime.h>
#include <hip/hip_bf16.h>

#define CH 512
#define BM 128
#define BN 64
#define BK 64
#define NT (CH / BK)

typedef __attribute__((ext_vector_type(8))) short short8;
typedef __attribute__((ext_vector_type(4))) float f32x4;

static __device__ __forceinline__ ushort f2b(float f) {
  union { __hip_bfloat16 b; ushort u; } c;
  c.b = __float2bfloat16(f);
  return c.u;
}
static __device__ __forceinline__ float blo(uint u) { return __uint_as_float(u << 16); }
static __device__ __forceinline__ float bhi(uint u) { return __uint_as_float(u & 0xffff0000u); }
static __device__ __forceinline__ uint pk2(float a, float b) {
  return (uint)f2b(a) | ((uint)f2b(b) << 16);
}

// edge convert + degree count; edge dtype (int64 vs int32) detected per-wave
__global__ void k_cvt_count(const int* ei, int* s32, int* d32,
                            int* outdeg, int* indeg, int E) {
  int e = blockIdx.x * blockDim.x + threadIdx.x;
  int lane = threadIdx.x & 63;
  int fl = 0;
  if (lane == 0) {
    int zeros = 0;
    for (int j = 1; j < 32; j += 2) zeros += (ei[j] == 0) ? 1 : 0;
    fl = (zeros >= 14) ? 1 : 0;
  }
  fl = __shfl(fl, 0);
  if (e >= E) return;
  int s, d;
  if (fl) {
    const long long* p = (const long long*)ei;
    s = (int)p[e];
    d = (int)p[e + E];
  } else {
    s = ei[e];
    d = ei[e + E];
  }
  s32[e] = s;
  d32[e] = d;
  atomicAdd(&outdeg[s], 1);
  atomicAdd(&indeg[d], 1);
}

// dinv + exclusive scan of (outdeg+1) in one launch
__global__ __launch_bounds__(1024) void k_scan(const int* outdeg, const int* indeg,
                                               float* dinv, int* rs, int* cursor, int N) {
  __shared__ int part[1024];
  int t = threadIdx.x;
  for (int i = t; i < N; i += 1024) dinv[i] = rsqrtf((float)(indeg[i] + 1));
  int per = (N + 1023) >> 10;
  int base = t * per;
  int s = 0;
  for (int j = 0; j < per; ++j) {
    int i = base + j;
    if (i < N) s += outdeg[i] + 1;  // +1 self loop
  }
  part[t] = s;
  __syncthreads();
  for (int off = 1; off < 1024; off <<= 1) {
    int v = part[t];
    int u = (t >= off) ? part[t - off] : 0;
    __syncthreads();
    part[t] = v + u;
    __syncthreads();
  }
  int run = (t == 0) ? 0 : part[t - 1];
  for (int j = 0; j < per; ++j) {
    int i = base + j;
    if (i < N) {
      rs[i] = run;
      cursor[i] = run;
      run += outdeg[i] + 1;
    }
  }
  if (t == 0) rs[N] = part[1023];
}

__global__ void k_fill(const int* s32, const int* d32, const float* dinv,
                       int* cursor, int* col, float* wgt, int E, int N) {
  int e = blockIdx.x * blockDim.x + threadIdx.x;
  if (e < E) {
    int s = s32[e], d = d32[e];
    int pos = atomicAdd(&cursor[s], 1);
    col[pos] = d;
    wgt[pos] = dinv[s] * dinv[d];
  } else if (e < E + N) {
    int i = e - E;
    int pos = atomicAdd(&cursor[i], 1);
    col[pos] = i;
    float di = dinv[i];
    wgt[pos] = di * di;
  }
}

// W[k][n] (512x512) -> WT[n][k] bf16, both weights in one launch
__global__ void k_cast_wt2(const float* W1, ushort* WT1, const float* W2, ushort* WT2) {
  int idx = blockIdx.x * blockDim.x + threadIdx.x;
  if (idx >= 2 * CH * CH) return;
  const float* W = (idx < CH * CH) ? W1 : W2;
  ushort* WT = (idx < CH * CH) ? WT1 : WT2;
  int j = idx & (CH * CH - 1);
  int n = j >> 9, k = j & 511;
  WT[j] = f2b(W[(k << 9) + n]);
}

// C[Mp,512] = A @ B(BT[n][k]) + bias -> bf16.  BM=128 BN=64 BK=64, dbuf LDS,
// XCD chunk-swizzled 1D grid, 4 waves (2Mx2N), wave-tile 64x32.
// A-path is REG-staged with fused transform:
//   AMODE=0: Asrc = f32 x, convert->bf16 in flight   (replaces cast_x)
//   AMODE=1: Asrc = bf16 a1, BN scale/shift+ReLU in flight (replaces bn_scale+bn_apply)
// B-path via global_load_lds (16B). Row clamp instead of zero-pad: pad A-rows
// only affect pad C-rows, which no downstream consumer reads.
template <int AMODE>
__global__ __launch_bounds__(256) void k_gemm(const void* __restrict__ Asrc,
                                              const ushort* __restrict__ BT,
                                              const float* __restrict__ bias,
                                              const float* __restrict__ stats,
                                              const float* __restrict__ gamma,
                                              const float* __restrict__ beta,
                                              float invN, ushort* __restrict__ Cout,
                                              int gy, int Nrows) {
  __shared__ __align__(16) ushort As[2][BM * BK];
  __shared__ __align__(16) ushort Bs[2][BN * BK];
  __shared__ float sc_l[CH], sh_l[CH];
  const int t = threadIdx.x;
  const int wave = t >> 6;
  const int lane = t & 63;
  const int l15 = lane & 15;
  const int lh = lane >> 4;
  const int wm = wave >> 1;   // 0..1 (M half)
  const int wn = wave & 1;    // 0..1 (N half)

  // bijective XCD chunk swizzle (m204): consecutive L share the A-panel (bx)
  int nwg = gridDim.x, wg = blockIdx.x;
  int xcd = wg & 7, i8 = wg >> 3;
  int q = nwg >> 3, r = nwg & 7;
  int L = ((xcd < r) ? xcd * (q + 1) : r * (q + 1) + (xcd - r) * q) + i8;
  int bx = L / gy, by = L % gy;
  const int row0 = bx * BM;
  const int col0 = by * BN;

  if (AMODE == 1) {
    #pragma unroll
    for (int c = t; c < CH; c += 256) {
      float mu = stats[c] * invN;
      float var = stats[CH + c] * invN - mu * mu;  // biased var (jnp.var)
      float s = gamma[c] * rsqrtf(var + 1e-5f);
      sc_l[c] = s;
      sh_l[c] = beta[c] - s * mu;
    }
    __syncthreads();
  }

  const int koff = ((t * 16) & 127) >> 1;  // element offset within row, 0..56 step 8
  const int rbase = t >> 3;                // 0..31

  float4 av[4][2];  // AMODE 0 staging regs
  uint4 au[4];      // AMODE 1 staging regs

  auto LDA = [&](int kt) {
    const int k0 = kt * BK;
    #pragma unroll
    for (int i = 0; i < 4; ++i) {
      int rg = row0 + i * 32 + rbase;
      rg = (rg < Nrows) ? rg : (Nrows - 1);
      if (AMODE == 0) {
        const float* p = (const float*)Asrc + (size_t)rg * CH + k0 + koff;
        av[i][0] = ((const float4*)p)[0];
        av[i][1] = ((const float4*)p)[1];
      } else {
        const uint* p = (const uint*)Asrc + (size_t)rg * (CH / 2) + ((k0 + koff) >> 1);
        au[i] = ((const uint4*)p)[0];
      }
    }
  };
  auto WRA = [&](int buf, int kt) {
    const int k0 = kt * BK;
    #pragma unroll
    for (int i = 0; i < 4; ++i) {
      uint4 w;
      if (AMODE == 0) {
        w.x = pk2(av[i][0].x, av[i][0].y);
        w.y = pk2(av[i][0].z, av[i][0].w);
        w.z = pk2(av[i][1].x, av[i][1].y);
        w.w = pk2(av[i][1].z, av[i][1].w);
      } else {
        int c0 = k0 + koff;
        float4 sa = *(const float4*)&sc_l[c0];
        float4 sb = *(const float4*)&sc_l[c0 + 4];
        float4 ha = *(const float4*)&sh_l[c0];
        float4 hb = *(const float4*)&sh_l[c0 + 4];
        w.x = pk2(fmaxf(blo(au[i].x) * sa.x + ha.x, 0.f), fmaxf(bhi(au[i].x) * sa.y + ha.y, 0.f));
        w.y = pk2(fmaxf(blo(au[i].y) * sa.z + ha.z, 0.f), fmaxf(bhi(au[i].y) * sa.w + ha.w, 0.f));
        w.z = pk2(fmaxf(blo(au[i].z) * sb.x + hb.x, 0.f), fmaxf(bhi(au[i].z) * sb.y + hb.y, 0.f));
        w.w = pk2(fmaxf(blo(au[i].w) * sb.z + hb.z, 0.f), fmaxf(bhi(au[i].w) * sb.w + hb.w, 0.f));
      }
      *(uint4*)((char*)As[buf] + i * 4096 + t * 16) = w;
    }
  };
  auto STB = [&](int buf, int kt) {
    const int k0 = kt * BK;
    #pragma unroll
    for (int i = 0; i < 2; ++i) {
      int o = i * 4096 + t * 16;
      int rowb = o >> 7, cb = o & 127;
      const ushort* sb = BT + (size_t)(col0 + rowb) * CH + k0 + (cb >> 1);
      __builtin_amdgcn_global_load_lds(
          (const __attribute__((address_space(1))) void*)sb,
          (__attribute__((address_space(3))) void*)((char*)Bs[buf] + o), 16, 0, 0);
    }
  };

  f32x4 acc[4][2] = {};

  LDA(0);
  STB(0, 0);
  WRA(0, 0);
  __syncthreads();

  #pragma unroll 2
  for (int kt = 0; kt < NT; ++kt) {
    int cur = kt & 1;
    if (kt + 1 < NT) { LDA(kt + 1); STB(cur ^ 1, kt + 1); }
    #pragma unroll
    for (int ks = 0; ks < 2; ++ks) {
      short8 af[4], bfr[2];
      #pragma unroll
      for (int mi = 0; mi < 4; ++mi)
        af[mi] = *(const short8*)&As[cur][(wm * 64 + mi * 16 + l15) * BK + ks * 32 + lh * 8];
      #pragma unroll
      for (int ni = 0; ni < 2; ++ni)
        bfr[ni] = *(const short8*)&Bs[cur][(wn * 32 + ni * 16 + l15) * BK + ks * 32 + lh * 8];
      #pragma unroll
      for (int mi = 0; mi < 4; ++mi)
        #pragma unroll
        for (int ni = 0; ni < 2; ++ni)
          acc[mi][ni] = __builtin_amdgcn_mfma_f32_16x16x32_bf16(af[mi], bfr[ni], acc[mi][ni], 0, 0, 0);
    }
    if (kt + 1 < NT) WRA(cur ^ 1, kt + 1);
    __syncthreads();
  }

  // C/D layout: col = lane&15, row = (lane>>4)*4 + reg  (verified m89/m91)
  #pragma unroll
  for (int ni = 0; ni < 2; ++ni) {
    int c = col0 + wn * 32 + ni * 16 + l15;
    float bi = bias[c];
    #pragma unroll
    for (int mi = 0; mi < 4; ++mi) {
      int row = row0 + wm * 64 + mi * 16 + lh * 4;
      #pragma unroll
      for (int r = 0; r < 4; ++r)
        Cout[(size_t)(row + r) * CH + c] = f2b(acc[mi][ni][r] + bi);
    }
  }
}

// Wave-per-node agg: out[i,:] = sum_j wgt[j] * h[col[j],:]
// col/wgt preloaded 1/lane + __shfl broadcast; 16B (uint4) gather per lane.
template <int OUTF>
__global__ __launch_bounds__(256) void k_agg_w(const ushort* __restrict__ h,
                                               const int* __restrict__ rs,
                                               const int* __restrict__ col,
                                               const float* __restrict__ wgt,
                                               void* __restrict__ out, int N) {
  int wv = (blockIdx.x << 2) + (threadIdx.x >> 6);
  if (wv >= N) return;
  int lane = threadIdx.x & 63;
  int beg = rs[wv], end = rs[wv + 1];
  const uint4* hb = (const uint4*)h;
  float a0 = 0.f, a1 = 0.f, a2 = 0.f, a3 = 0.f, a4 = 0.f, a5 = 0.f, a6 = 0.f, a7 = 0.f;
  for (int base = beg; base < end; base += 64) {
    int j = base + lane;
    int cl = 0;
    float wl = 0.f;
    if (j < end) { cl = col[j]; wl = wgt[j]; }
    int cnt = min(64, end - base);
    for (int jj = 0; jj < cnt; ++jj) {
      int c = __shfl(cl, jj);
      float w = __shfl(wl, jj);
      uint4 u = hb[(size_t)c * 64 + lane];
      a0 += w * blo(u.x); a1 += w * bhi(u.x);
      a2 += w * blo(u.y); a3 += w * bhi(u.y);
      a4 += w * blo(u.z); a5 += w * bhi(u.z);
      a6 += w * blo(u.w); a7 += w * bhi(u.w);
    }
  }
  if (OUTF) {
    float4* o = (float4*)out;
    o[(size_t)wv * 128 + lane * 2]     = (float4){ a0, a1, a2, a3 };
    o[(size_t)wv * 128 + lane * 2 + 1] = (float4){ a4, a5, a6, a7 };
  } else {
    uint4 o = { pk2(a0, a1), pk2(a2, a3), pk2(a4, a5), pk2(a6, a7) };
    ((uint4*)out)[(size_t)wv * 64 + lane] = o;
  }
}

__global__ __launch_bounds__(256) void k_bn_stats(const ushort* __restrict__ a,
                                                  float* __restrict__ stats, int N) {
  int t = threadIdx.x;
  const uint* ab = (const uint*)a;
  float s0 = 0.f, q0 = 0.f, s1 = 0.f, q1 = 0.f;
  for (int i = blockIdx.x; i < N; i += gridDim.x) {
    uint u = ab[(size_t)i * 256 + t];
    float lo = blo(u), hi = bhi(u);
    s0 += lo; q0 += lo * lo;
    s1 += hi; q1 += hi * hi;
  }
  atomicAdd(&stats[2 * t], s0);
  atomicAdd(&stats[2 * t + 1], s1);
  atomicAdd(&stats[CH + 2 * t], q0);
  atomicAdd(&stats[CH + 2 * t + 1], q1);
}

extern "C" void kernel_launch(void* const* d_in, const int* in_sizes, int n_in,
                              void* d_out, int out_size, void* d_ws, size_t ws_size,
                              hipStream_t stream) {
  const float* x     = (const float*)d_in[0];
  const float* W1    = (const float*)d_in[1];
  const float* b1    = (const float*)d_in[2];
  const float* gamma = (const float*)d_in[3];
  const float* beta  = (const float*)d_in[4];
  const float* W2    = (const float*)d_in[5];
  const float* b2    = (const float*)d_in[6];
  const int*   ei    = (const int*)d_in[7];
  const int N = in_sizes[0] / CH;
  const int E = in_sizes[7] / 2;
  const int Mp = ((N + BM - 1) / BM) * BM;   // padded row count
  float* out = (float*)d_out;

  char* wsp = (char*)d_ws;
  size_t off = 0;
  auto alloc = [&](size_t b) { char* p = wsp + off; off += (b + 255) & ~(size_t)255; return p; };
  int*    outdeg = (int*)alloc((size_t)N * 4);   // memset-zeroed below
  int*    indeg  = (int*)alloc((size_t)N * 4);   // memset-zeroed below
  float*  stats  = (float*)alloc(1024 * 4);      // memset-zeroed below
  int*    s32    = (int*)alloc((size_t)E * 4);
  int*    d32    = (int*)alloc((size_t)E * 4);
  float*  dinv   = (float*)alloc((size_t)N * 4);
  int*    rs     = (int*)alloc((size_t)(N + 1) * 4);
  int*    cursor = (int*)alloc((size_t)N * 4);
  int*    colx   = (int*)alloc((size_t)(E + N) * 4);
  float*  wgt    = (float*)alloc((size_t)(E + N) * 4);
  ushort* w1t    = (ushort*)alloc((size_t)CH * CH * 2);
  ushort* w2t    = (ushort*)alloc((size_t)CH * CH * 2);
  ushort* h1b    = (ushort*)alloc((size_t)Mp * CH * 2);  // GEMM1 out (bf16)
  ushort* a1b    = (ushort*)alloc((size_t)N * CH * 2);   // agg1 out (bf16)
  ushort* h2b    = (ushort*)alloc((size_t)Mp * CH * 2);  // GEMM2 out (bf16)

  // zero [outdeg .. stats] (contiguous at ws base) via DMA
  size_t zbytes = (size_t)((char*)(stats + 1024) - (char*)outdeg);
  hipMemsetAsync(outdeg, 0, zbytes, stream);

  int eb = (E + 255) / 256;
  k_cvt_count<<<eb, 256, 0, stream>>>(ei, s32, d32, outdeg, indeg, E);
  k_scan<<<1, 1024, 0, stream>>>(outdeg, indeg, dinv, rs, cursor, N);
  k_fill<<<(E + N + 255) / 256, 256, 0, stream>>>(s32, d32, dinv, cursor, colx, wgt, E, N);
  k_cast_wt2<<<(2 * CH * CH + 255) / 256, 256, 0, stream>>>(W1, w1t, W2, w2t);
  int gy = CH / BN;
  int ngemm = (Mp / BM) * gy;
  int ab = (N + 3) / 4;
  k_gemm<0><<<ngemm, 256, 0, stream>>>(x, w1t, b1, nullptr, nullptr, nullptr,
                                       0.f, h1b, gy, N);
  k_agg_w<0><<<ab, 256, 0, stream>>>(h1b, rs, colx, wgt, a1b, N);
  k_bn_stats<<<256, 256, 0, stream>>>(a1b, stats, N);
  k_gemm<1><<<ngemm, 256, 0, stream>>>(a1b, w2t, b2, stats, gamma, beta,
                                       1.0f / (float)N, h2b, gy, N);
  k_agg_w<1><<<ab, 256, 0, stream>>>(h2b, rs, colx, wgt, out, N);
}